// Round 11
// baseline (940.967 us; speedup 1.0000x reference)
//
#include <hip/hip_runtime.h>
#include <stdint.h>

// W8A16 quantized linear, two-phase:
//   Pre-pass: A f32->f16 (64 MB), W = fp16(q*scale) (32 MB) into d_ws.
//   GEMM:     256x256 tile, BK=32, 8 waves (2M x 4N), wave tile 128x64
//             (acc[8][4]), FOUR LDS buffers (32 KB/set), 2 phases/K-tile,
//             balanced reads (4 then 8 per wave), 1-phase frag lookahead,
//             2-tile stage lookahead, counted lgkm/vm waits, raw s_barrier,
//             setprio. __launch_bounds__(512,2).
// LDS map (packed-pair, per 16 KB buffer): global row r, k-slot s(0..3,8f16)
//   -> line L=r>>1, w=(r&1)*4+s, phys slot w^=L&7, byte = L*128 + w'*16.
//   Bijective wave access (64 lanes <-> 64 line/slot cells) -> 0 conflicts.
//   Staged via global_load_lds(16B) linear dest + inverse-map global source.
// lgkm ledger (b128 units): enter p1: [af_top 4, bf 4]; p1 +af_bot 4,
//   LGKM(4) retires af_top+bf -> MFMA top; p2 reads af_top'+bf' (8, nxt),
//   LGKM(8) retires af_bot -> MFMA bottom.
// vm ledger (stage insts): enter p1: [A(kt+1) 2, B(kt+1) 2]; p1 +A(kt+2);
//   p2 +B(kt+2), VMW(4) retires kt+1 (slack ~2 tiles); tail: VMW(0).

#define M_DIM 8192
#define N_DIM 4096
#define K_DIM 4096
#define BM 256
#define BN 256
#define BK 32
#define NKT (K_DIM / BK)   // 128 K-tiles

typedef _Float16 f16;
typedef f16 f16x8 __attribute__((ext_vector_type(8)));
typedef f16 f16x2 __attribute__((ext_vector_type(2)));
typedef float f32x4 __attribute__((ext_vector_type(4)));

static __device__ __forceinline__ f16x2 cvt2(float a, float b) {
  return __builtin_bit_cast(f16x2, __builtin_amdgcn_cvt_pkrtz(a, b));
}

// ---------------- pre-pass kernels ----------------

__global__ __launch_bounds__(256) void conv_a_kernel(
    const float* __restrict__ A, f16* __restrict__ Af)
{
  const size_t stride = (size_t)gridDim.x * blockDim.x;
  size_t i = (size_t)blockIdx.x * blockDim.x + threadIdx.x;
  const size_t n8 = (size_t)M_DIM * K_DIM / 8;
  for (; i < n8; i += stride) {
    const f32x4* p = (const f32x4*)(A + i * 8);
    f32x4 v0 = p[0], v1 = p[1];
    f16x2 a = cvt2(v0.x, v0.y), b = cvt2(v0.z, v0.w);
    f16x2 c = cvt2(v1.x, v1.y), d = cvt2(v1.z, v1.w);
    *(f16x8*)(Af + i * 8) = (f16x8){a.x, a.y, b.x, b.y, c.x, c.y, d.x, d.y};
  }
}

__global__ __launch_bounds__(256) void conv_b_kernel(
    const int* __restrict__ Qw, const float* __restrict__ Sc,
    f16* __restrict__ Wf)
{
  const int o = blockIdx.x;
  const int t = threadIdx.x;
  const float s = Sc[o];
  const int* q = Qw + (size_t)o * K_DIM + t * 16;
  f16* w = Wf + (size_t)o * K_DIM + t * 16;
  #pragma unroll
  for (int h = 0; h < 2; ++h) {
    int4 u0 = *(const int4*)(q + h * 8);
    int4 u1 = *(const int4*)(q + h * 8 + 4);
    f16x2 a = cvt2((float)u0.x * s, (float)u0.y * s);
    f16x2 b = cvt2((float)u0.z * s, (float)u0.w * s);
    f16x2 c = cvt2((float)u1.x * s, (float)u1.y * s);
    f16x2 d = cvt2((float)u1.z * s, (float)u1.w * s);
    *(f16x8*)(w + h * 8) = (f16x8){a.x, a.y, b.x, b.y, c.x, c.y, d.x, d.y};
  }
}

// ---------------- main GEMM ----------------

#define BARX() __builtin_amdgcn_s_barrier()
#define SCHED0() __builtin_amdgcn_sched_barrier(0)
#define LGKM(n) do { asm volatile("s_waitcnt lgkmcnt(" #n ")" ::: "memory"); \
                     __builtin_amdgcn_sched_barrier(0); } while (0)
#define VMW(n)  do { asm volatile("s_waitcnt vmcnt(" #n ")" ::: "memory"); \
                     __builtin_amdgcn_sched_barrier(0); } while (0)

// stage one 256x32 f16 tile (16 KB): 2 x global_load_lds(16B)/thread,
// linear LDS dest, inverse-mapped global source (packed-pair XOR layout)
#define STAGE_A(bi, ktn) do { \
  _Pragma("unroll") \
  for (int _i = 0; _i < 2; ++_i) { \
    const f16* _g = aSrc + (size_t)((st_R + 64 * _i) * 2 + st_h) * K_DIM \
                    + (ktn) * BK + st_s * 8; \
    char* _l = (char*)&As[bi][0] + _i * 8192 + wid * 1024; \
    __builtin_amdgcn_global_load_lds( \
        (const __attribute__((address_space(1))) void*)_g, \
        (__attribute__((address_space(3))) void*)_l, 16, 0, 0); \
  } } while (0)

#define STAGE_B(bi, ktn) do { \
  _Pragma("unroll") \
  for (int _i = 0; _i < 2; ++_i) { \
    const f16* _g = bSrc + (size_t)((st_R + 64 * _i) * 2 + st_h) * K_DIM \
                    + (ktn) * BK + st_s * 8; \
    char* _l = (char*)&Bs[bi][0] + _i * 8192 + wid * 1024; \
    __builtin_amdgcn_global_load_lds( \
        (const __attribute__((address_space(1))) void*)_g, \
        (__attribute__((address_space(3))) void*)_l, 16, 0, 0); \
  } } while (0)

// 4 ds_read_b128: A m-frags jb..jb+3 from buffer base
#define READ_AF(dst, jb, base_) do { \
  _Pragma("unroll") \
  for (int _m = 0; _m < 4; ++_m) \
    dst[_m] = *(const f16x8*)((base_) + a_rd[(jb) + _m]); \
  } while (0)

// 4 ds_read_b128: B n-frags
#define READ_BF(dst, base_) do { \
  _Pragma("unroll") \
  for (int _n = 0; _n < 4; ++_n) \
    dst[_n] = *(const f16x8*)((base_) + b_rd[_n]); \
  } while (0)

// 16 MFMA: m-frags jb..jb+3 x 4 n-frags
#define MFMA_HALF(jb, A_, B_) do { \
  __builtin_amdgcn_s_setprio(1); \
  _Pragma("unroll") \
  for (int _m = 0; _m < 4; ++_m) \
    _Pragma("unroll") \
    for (int _n = 0; _n < 4; ++_n) \
      acc[(jb) + _m][_n] = __builtin_amdgcn_mfma_f32_16x16x32_f16( \
          A_[_m], B_[_n], acc[(jb) + _m][_n], 0, 0, 0); \
  __builtin_amdgcn_s_setprio(0); } while (0)

// One K-tile: CB=cur buf, NB=(CB+1)&3, SB=(CB+2)&3; BFC cur B-frags, BFN next
#define TILE(KT, CB, NB, SB, BFC, BFN) do { \
  const bool _m1 = (KT) + 1 < NKT; \
  const bool _m2 = (KT) + 2 < NKT; \
  const char* _ac = (const char*)&As[CB][0]; \
  /* p1: stage A(kt+2); read af_bot(cur); MFMA top */ \
  if (_m2) STAGE_A(SB, (KT) + 2); \
  READ_AF(af_bot, 4, _ac); \
  BARX(); \
  LGKM(4); \
  MFMA_HALF(0, af_top, BFC); \
  BARX(); \
  /* p2: stage B(kt+2); seal kt+1; read af_top'+bf'(nxt); MFMA bottom */ \
  if (_m2) { STAGE_B(SB, (KT) + 2); VMW(4); } \
  else     { VMW(0); } \
  BARX(); SCHED0(); \
  if (_m1) { \
    READ_AF(af_top, 0, (const char*)&As[NB][0]); \
    READ_BF(BFN, (const char*)&Bs[NB][0]); \
    LGKM(8); \
  } else { LGKM(0); } \
  MFMA_HALF(4, af_bot, BFC); \
  BARX(); \
} while (0)

__global__ __launch_bounds__(512, 2) void w8a16_gemm_f16_kernel(
    const f16* __restrict__ Af,   // [M][K]
    const f16* __restrict__ Wf,   // [N][K], scale folded
    float* __restrict__ Out)      // [M][N]
{
  // 4 buffers x 16 KB each operand = 128 KB
  __shared__ __align__(16) f16 As[4][BM * BK];
  __shared__ __align__(16) f16 Bs[4][BN * BK];

  const int t    = threadIdx.x;
  const int lane = t & 63;
  const int wid  = t >> 6;       // 0..7
  const int wm   = wid >> 2;     // 0..1 (M interleave)
  const int wn   = wid & 3;      // 0..3 (N interleave)
  const int fr   = lane & 15;
  const int qk   = lane >> 4;    // k-slot 0..3

  // staging map (thread t, inst i): phys slot f = t + i*512;
  // L=f>>3, w'=f&7, w=w'^(L&7): row=(st_R+64i)*2+st_h, k-slot st_s
  const int st_R = t >> 3;
  const int st_x = (t & 7) ^ (st_R & 7);
  const int st_h = st_x >> 2;
  const int st_s = st_x & 3;

  // fragment read byte offsets (packed-pair XOR layout)
  int a_rd[8], b_rd[4];
  #pragma unroll
  for (int j = 0; j < 8; ++j) {
    const int r = (2 * j + wm) * 16 + fr;
    a_rd[j] = (r >> 1) * 128 + (((((r & 1) << 2) | qk) ^ ((r >> 1) & 7)) << 4);
  }
  #pragma unroll
  for (int n = 0; n < 4; ++n) {
    const int r = n * 64 + wn * 16 + fr;
    b_rd[n] = (r >> 1) * 128 + (((((r & 1) << 2) | qk) ^ ((r >> 1) & 7)) << 4);
  }

  // XCD swizzle: 512 blocks, %8==0 -> simple bijective form
  const int bid = blockIdx.x;
  const int swz = (bid & 7) * 64 + (bid >> 3);
  const int tn  = swz & 15;      // 16 N-tiles
  const int tm  = swz >> 4;      // 32 M-tiles

  const f16* aSrc = Af + (size_t)tm * BM * K_DIM;
  const f16* bSrc = Wf + (size_t)tn * BN * K_DIM;

  f32x4 acc[8][4] = {};
  f16x8 af_top[4], af_bot[4], bfA[4], bfB[4];

  // prologue: stage kt0 -> buf0, kt1 -> buf1; confirm kt0; lookahead reads
  STAGE_A(0, 0); STAGE_B(0, 0);
  STAGE_A(1, 1); STAGE_B(1, 1);
  VMW(4);
  BARX(); SCHED0();
  READ_AF(af_top, 0, (const char*)&As[0][0]);
  READ_BF(bfA, (const char*)&Bs[0][0]);

  for (int kt = 0; kt < NKT; kt += 4) {
    TILE(kt    , 0, 1, 2, bfA, bfB);
    TILE(kt + 1, 1, 2, 3, bfB, bfA);
    TILE(kt + 2, 2, 3, 0, bfA, bfB);
    TILE(kt + 3, 3, 0, 1, bfB, bfA);
  }

  // epilogue: C/D col = lane&15, row = (lane>>4)*4 + reg
  const int fq = lane >> 4;
  #pragma unroll
  for (int mi = 0; mi < 8; ++mi) {
    const size_t row = (size_t)tm * BM + (2 * mi + wm) * 16 + fq * 4;
    #pragma unroll
    for (int ni = 0; ni < 4; ++ni) {
      const size_t col = (size_t)tn * BN + ni * 64 + wn * 16 + fr;
      #pragma unroll
      for (int r = 0; r < 4; ++r)
        Out[(row + r) * N_DIM + col] = acc[mi][ni][r];
    }
  }
}

// ---------------- fallback (round-3 verified path) ----------------

__global__ __launch_bounds__(256) void w8a16_gemm_fb_kernel(
    const float* __restrict__ A, const int* __restrict__ Qw,
    const float* __restrict__ Sc, float* __restrict__ Out)
{
  __shared__ __align__(16) float Asf[2][128 * 32];
  __shared__ __align__(16) f16 Bsf[2][128][32];

  const int t = threadIdx.x, lane = t & 63, wid = t >> 6;
  const int wr = wid >> 1, wc = wid & 1;
  const int nwg = gridDim.x, cpx = nwg >> 3, bid = blockIdx.x;
  const int swz = (bid & 7) * cpx + (bid >> 3);
  const int tn = swz & 31, tm = swz >> 5;
  const size_t a_base = (size_t)tm * 128 * K_DIM;
  const size_t b_base = (size_t)tn * 128 * K_DIM;
  f32x4 acc[4][4] = {};
  const int a_r = t >> 3;
  const int a_slog = (t & 7) ^ ((t >> 3) & 7);

  auto stageA = [&](int buf, int kt) {
    #pragma unroll
    for (int c = 0; c < 4; ++c) {
      const float* g = A + a_base + (size_t)(c * 32 + a_r) * K_DIM + kt * 32 + a_slog * 4;
      char* l = (char*)&Asf[buf][0] + c * 4096 + wid * 1024;
      __builtin_amdgcn_global_load_lds(
          (const __attribute__((address_space(1))) void*)g,
          (__attribute__((address_space(3))) void*)l, 16, 0, 0);
    }
  };
  const int b_r = t >> 3, b_col = (t & 7) * 4;
  auto loadB = [&](int kt, int4* v) {
    #pragma unroll
    for (int c = 0; c < 4; ++c)
      v[c] = *(const int4*)(Qw + b_base + (size_t)(c * 32 + b_r) * K_DIM + kt * 32 + b_col);
  };
  auto writeB = [&](int buf, const int4* v) {
    #pragma unroll
    for (int c = 0; c < 4; ++c) {
      f16x2 lo = cvt2((float)v[c].x, (float)v[c].y);
      f16x2 hi = cvt2((float)v[c].z, (float)v[c].w);
      *(f16x2*)&Bsf[buf][c * 32 + b_r][b_col] = lo;
      *(f16x2*)&Bsf[buf][c * 32 + b_r][b_col + 2] = hi;
    }
  };
  auto compute = [&](int buf) {
    const int fr2 = lane & 15, q = lane >> 4;
    f16x8 af2[4], bf2[4];
    #pragma unroll
    for (int i = 0; i < 4; ++i) {
      const int r = wr * 64 + i * 16 + fr2;
      const float* base = &Asf[buf][0] + r * 32;
      const int s0 = q * 2;
      f32x4 a0 = *(const f32x4*)(base + ((s0 ^ (r & 7)) * 4));
      f32x4 a1 = *(const f32x4*)(base + (((s0 + 1) ^ (r & 7)) * 4));
      f16x2 p0 = cvt2(a0.x, a0.y), p1 = cvt2(a0.z, a0.w);
      f16x2 p2 = cvt2(a1.x, a1.y), p3 = cvt2(a1.z, a1.w);
      af2[i] = (f16x8){p0.x, p0.y, p1.x, p1.y, p2.x, p2.y, p3.x, p3.y};
      bf2[i] = *(const f16x8*)&Bsf[buf][wc * 64 + i * 16 + fr2][q * 8];
    }
    #pragma unroll
    for (int mi = 0; mi < 4; ++mi)
      #pragma unroll
      for (int ni = 0; ni < 4; ++ni)
        acc[mi][ni] = __builtin_amdgcn_mfma_f32_16x16x32_f16(
            af2[mi], bf2[ni], acc[mi][ni], 0, 0, 0);
  };

  { int4 b0[4]; stageA(0, 0); loadB(0, b0); writeB(0, b0); }
  __syncthreads();
  for (int kt = 0; kt < K_DIM / 32; ++kt) {
    const int buf = kt & 1;
    const bool more = (kt + 1) < K_DIM / 32;
    int4 nb[4];
    if (more) { stageA(buf ^ 1, kt + 1); loadB(kt + 1, nb); }
    compute(buf);
    if (more) writeB(buf ^ 1, nb);
    __syncthreads();
  }
  const int fr2 = lane & 15, fq = lane >> 4;
  const int cb = tn * 128 + wc * 64 + fr2;
  const int rb = tm * 128 + wr * 64 + fq * 4;
  #pragma unroll
  for (int ni = 0; ni < 4; ++ni) {
    const float s = Sc[cb + ni * 16];
    #pragma unroll
    for (int mi = 0; mi < 4; ++mi)
      #pragma unroll
      for (int r = 0; r < 4; ++r)
        Out[(size_t)(rb + mi * 16 + r) * N_DIM + (cb + ni * 16)] =
            acc[mi][ni][r] * s;
  }
}

extern "C" void kernel_launch(void* const* d_in, const int* in_sizes, int n_in,
                              void* d_out, int out_size, void* d_ws, size_t ws_size,
                              hipStream_t stream) {
  const float* A  = (const float*)d_in[0];
  const int*   Qw = (const int*)d_in[1];
  const float* Sc = (const float*)d_in[2];
  float*       Out = (float*)d_out;

  const size_t a_bytes = (size_t)M_DIM * K_DIM * sizeof(f16);  // 64 MB
  const size_t w_bytes = (size_t)N_DIM * K_DIM * sizeof(f16);  // 32 MB

  if (ws_size >= a_bytes + w_bytes) {
    f16* Af = (f16*)d_ws;
    f16* Wf = (f16*)((char*)d_ws + a_bytes);
    conv_a_kernel<<<2048, 256, 0, stream>>>(A, Af);
    conv_b_kernel<<<N_DIM, 256, 0, stream>>>(Qw, Sc, Wf);
    dim3 grid((M_DIM / BM) * (N_DIM / BN));  // 32*16 = 512
    w8a16_gemm_f16_kernel<<<grid, 512, 0, stream>>>(Af, Wf, Out);
  } else {
    dim3 grid((M_DIM / 128) * (N_DIM / 128));
    w8a16_gemm_fb_kernel<<<grid, 256, 0, stream>>>(A, Qw, Sc, Out);
  }
}

// Round 12
// 940.405 us; speedup vs baseline: 1.0006x; 1.0006x over previous
//
#include <hip/hip_runtime.h>
#include <stdint.h>

// W8A16 quantized linear, two-phase:
//   Pre-pass: A f32->f16 (64 MB), W = fp16(q*scale) (32 MB) into d_ws.
//   GEMM:     256x256 tile, BK=32, 8 waves (2M x 4N), wave tile 128x64
//             (acc[8][4]), FOUR LDS buffers (32 KB/set), 2 phases/K-tile,
//             balanced reads (4 then 8 per wave), 1-phase frag lookahead,
//             2-tile stage lookahead, counted lgkm/vm waits, raw s_barrier,
//             setprio. __launch_bounds__(512,1): R11 used (512,2) which this
//             compiler treats as 2 blocks/CU -> 128-VGPR cap -> acc spilled
//             (WRITE_SIZE 807 MB). LDS=128KB already limits to 1 block/CU,
//             so (512,1) costs nothing and allows the ~220 VGPRs needed.
// LDS map (packed-pair, per 16 KB buffer): global row r, k-slot s(0..3,8f16)
//   -> line L=r>>1, w=(r&1)*4+s, phys slot w^=L&7, byte = L*128 + w'*16.
//   Bijective wave access (64 lanes <-> 64 line/slot cells) -> 0 conflicts
//   (verified: R10/R11 SQ_LDS_BANK_CONFLICT = 0).
// lgkm ledger (b128 units): enter p1: [af_top 4, bf 4]; p1 +af_bot 4,
//   LGKM(4) retires af_top+bf -> MFMA top; p2 reads af_top'+bf' (8, nxt),
//   LGKM(8) retires af_bot -> MFMA bottom.
// vm ledger (stage insts): enter p1: [A(kt+1) 2, B(kt+1) 2]; p1 +A(kt+2);
//   p2 +B(kt+2), VMW(4) retires kt+1 (slack ~2 tiles); tail: VMW(0).
// WAR: buffer X (holding kt-2) last read at p2(kt-2) (LGKM(8) retires),
//   sealed by end-of-(kt-2) barrier; restaged at p1(kt) — >=1 tile later.

#define M_DIM 8192
#define N_DIM 4096
#define K_DIM 4096
#define BM 256
#define BN 256
#define BK 32
#define NKT (K_DIM / BK)   // 128 K-tiles

typedef _Float16 f16;
typedef f16 f16x8 __attribute__((ext_vector_type(8)));
typedef f16 f16x2 __attribute__((ext_vector_type(2)));
typedef float f32x4 __attribute__((ext_vector_type(4)));

static __device__ __forceinline__ f16x2 cvt2(float a, float b) {
  return __builtin_bit_cast(f16x2, __builtin_amdgcn_cvt_pkrtz(a, b));
}

// ---------------- pre-pass kernels ----------------

__global__ __launch_bounds__(256) void conv_a_kernel(
    const float* __restrict__ A, f16* __restrict__ Af)
{
  const size_t stride = (size_t)gridDim.x * blockDim.x;
  size_t i = (size_t)blockIdx.x * blockDim.x + threadIdx.x;
  const size_t n8 = (size_t)M_DIM * K_DIM / 8;
  for (; i < n8; i += stride) {
    const f32x4* p = (const f32x4*)(A + i * 8);
    f32x4 v0 = p[0], v1 = p[1];
    f16x2 a = cvt2(v0.x, v0.y), b = cvt2(v0.z, v0.w);
    f16x2 c = cvt2(v1.x, v1.y), d = cvt2(v1.z, v1.w);
    *(f16x8*)(Af + i * 8) = (f16x8){a.x, a.y, b.x, b.y, c.x, c.y, d.x, d.y};
  }
}

__global__ __launch_bounds__(256) void conv_b_kernel(
    const int* __restrict__ Qw, const float* __restrict__ Sc,
    f16* __restrict__ Wf)
{
  const int o = blockIdx.x;
  const int t = threadIdx.x;
  const float s = Sc[o];
  const int* q = Qw + (size_t)o * K_DIM + t * 16;
  f16* w = Wf + (size_t)o * K_DIM + t * 16;
  #pragma unroll
  for (int h = 0; h < 2; ++h) {
    int4 u0 = *(const int4*)(q + h * 8);
    int4 u1 = *(const int4*)(q + h * 8 + 4);
    f16x2 a = cvt2((float)u0.x * s, (float)u0.y * s);
    f16x2 b = cvt2((float)u0.z * s, (float)u0.w * s);
    f16x2 c = cvt2((float)u1.x * s, (float)u1.y * s);
    f16x2 d = cvt2((float)u1.z * s, (float)u1.w * s);
    *(f16x8*)(w + h * 8) = (f16x8){a.x, a.y, b.x, b.y, c.x, c.y, d.x, d.y};
  }
}

// ---------------- main GEMM ----------------

#define BARX() __builtin_amdgcn_s_barrier()
#define SCHED0() __builtin_amdgcn_sched_barrier(0)
#define LGKM(n) do { asm volatile("s_waitcnt lgkmcnt(" #n ")" ::: "memory"); \
                     __builtin_amdgcn_sched_barrier(0); } while (0)
#define VMW(n)  do { asm volatile("s_waitcnt vmcnt(" #n ")" ::: "memory"); \
                     __builtin_amdgcn_sched_barrier(0); } while (0)

// stage one 256x32 f16 tile (16 KB): 2 x global_load_lds(16B)/thread,
// linear LDS dest, inverse-mapped global source (packed-pair XOR layout)
#define STAGE_A(bi, ktn) do { \
  _Pragma("unroll") \
  for (int _i = 0; _i < 2; ++_i) { \
    const f16* _g = aSrc + (size_t)((st_R + 64 * _i) * 2 + st_h) * K_DIM \
                    + (ktn) * BK + st_s * 8; \
    char* _l = (char*)&As[bi][0] + _i * 8192 + wid * 1024; \
    __builtin_amdgcn_global_load_lds( \
        (const __attribute__((address_space(1))) void*)_g, \
        (__attribute__((address_space(3))) void*)_l, 16, 0, 0); \
  } } while (0)

#define STAGE_B(bi, ktn) do { \
  _Pragma("unroll") \
  for (int _i = 0; _i < 2; ++_i) { \
    const f16* _g = bSrc + (size_t)((st_R + 64 * _i) * 2 + st_h) * K_DIM \
                    + (ktn) * BK + st_s * 8; \
    char* _l = (char*)&Bs[bi][0] + _i * 8192 + wid * 1024; \
    __builtin_amdgcn_global_load_lds( \
        (const __attribute__((address_space(1))) void*)_g, \
        (__attribute__((address_space(3))) void*)_l, 16, 0, 0); \
  } } while (0)

// 4 ds_read_b128: A m-frags jb..jb+3 from buffer base
#define READ_AF(dst, jb, base_) do { \
  _Pragma("unroll") \
  for (int _m = 0; _m < 4; ++_m) \
    dst[_m] = *(const f16x8*)((base_) + a_rd[(jb) + _m]); \
  } while (0)

// 4 ds_read_b128: B n-frags
#define READ_BF(dst, base_) do { \
  _Pragma("unroll") \
  for (int _n = 0; _n < 4; ++_n) \
    dst[_n] = *(const f16x8*)((base_) + b_rd[_n]); \
  } while (0)

// 16 MFMA: m-frags jb..jb+3 x 4 n-frags
#define MFMA_HALF(jb, A_, B_) do { \
  __builtin_amdgcn_s_setprio(1); \
  _Pragma("unroll") \
  for (int _m = 0; _m < 4; ++_m) \
    _Pragma("unroll") \
    for (int _n = 0; _n < 4; ++_n) \
      acc[(jb) + _m][_n] = __builtin_amdgcn_mfma_f32_16x16x32_f16( \
          A_[_m], B_[_n], acc[(jb) + _m][_n], 0, 0, 0); \
  __builtin_amdgcn_s_setprio(0); } while (0)

// One K-tile: CB=cur buf, NB=(CB+1)&3, SB=(CB+2)&3; BFC cur B-frags, BFN next
#define TILE(KT, CB, NB, SB, BFC, BFN) do { \
  const bool _m1 = (KT) + 1 < NKT; \
  const bool _m2 = (KT) + 2 < NKT; \
  const char* _ac = (const char*)&As[CB][0]; \
  /* p1: stage A(kt+2); read af_bot(cur); MFMA top */ \
  if (_m2) STAGE_A(SB, (KT) + 2); \
  READ_AF(af_bot, 4, _ac); \
  BARX(); \
  LGKM(4); \
  MFMA_HALF(0, af_top, BFC); \
  BARX(); \
  /* p2: stage B(kt+2); seal kt+1; read af_top'+bf'(nxt); MFMA bottom */ \
  if (_m2) { STAGE_B(SB, (KT) + 2); VMW(4); } \
  else     { VMW(0); } \
  BARX(); SCHED0(); \
  if (_m1) { \
    READ_AF(af_top, 0, (const char*)&As[NB][0]); \
    READ_BF(BFN, (const char*)&Bs[NB][0]); \
    LGKM(8); \
  } else { LGKM(0); } \
  MFMA_HALF(4, af_bot, BFC); \
  BARX(); \
} while (0)

__global__ __launch_bounds__(512, 1) void w8a16_gemm_f16_kernel(
    const f16* __restrict__ Af,   // [M][K]
    const f16* __restrict__ Wf,   // [N][K], scale folded
    float* __restrict__ Out)      // [M][N]
{
  // 4 buffers x 16 KB each operand = 128 KB
  __shared__ __align__(16) f16 As[4][BM * BK];
  __shared__ __align__(16) f16 Bs[4][BN * BK];

  const int t    = threadIdx.x;
  const int lane = t & 63;
  const int wid  = t >> 6;       // 0..7
  const int wm   = wid >> 2;     // 0..1 (M interleave)
  const int wn   = wid & 3;      // 0..3 (N interleave)
  const int fr   = lane & 15;
  const int qk   = lane >> 4;    // k-slot 0..3

  // staging map (thread t, inst i): phys slot f = t + i*512;
  // L=f>>3, w'=f&7, w=w'^(L&7): row=(st_R+64i)*2+st_h, k-slot st_s
  const int st_R = t >> 3;
  const int st_x = (t & 7) ^ (st_R & 7);
  const int st_h = st_x >> 2;
  const int st_s = st_x & 3;

  // fragment read byte offsets (packed-pair XOR layout)
  int a_rd[8], b_rd[4];
  #pragma unroll
  for (int j = 0; j < 8; ++j) {
    const int r = (2 * j + wm) * 16 + fr;
    a_rd[j] = (r >> 1) * 128 + (((((r & 1) << 2) | qk) ^ ((r >> 1) & 7)) << 4);
  }
  #pragma unroll
  for (int n = 0; n < 4; ++n) {
    const int r = n * 64 + wn * 16 + fr;
    b_rd[n] = (r >> 1) * 128 + (((((r & 1) << 2) | qk) ^ ((r >> 1) & 7)) << 4);
  }

  // XCD swizzle: 512 blocks, %8==0 -> simple bijective form
  const int bid = blockIdx.x;
  const int swz = (bid & 7) * 64 + (bid >> 3);
  const int tn  = swz & 15;      // 16 N-tiles
  const int tm  = swz >> 4;      // 32 M-tiles

  const f16* aSrc = Af + (size_t)tm * BM * K_DIM;
  const f16* bSrc = Wf + (size_t)tn * BN * K_DIM;

  f32x4 acc[8][4] = {};
  f16x8 af_top[4], af_bot[4], bfA[4], bfB[4];

  // prologue: stage kt0 -> buf0, kt1 -> buf1; confirm kt0; lookahead reads
  STAGE_A(0, 0); STAGE_B(0, 0);
  STAGE_A(1, 1); STAGE_B(1, 1);
  VMW(4);
  BARX(); SCHED0();
  READ_AF(af_top, 0, (const char*)&As[0][0]);
  READ_BF(bfA, (const char*)&Bs[0][0]);

  for (int kt = 0; kt < NKT; kt += 4) {
    TILE(kt    , 0, 1, 2, bfA, bfB);
    TILE(kt + 1, 1, 2, 3, bfB, bfA);
    TILE(kt + 2, 2, 3, 0, bfA, bfB);
    TILE(kt + 3, 3, 0, 1, bfB, bfA);
  }

  // epilogue: C/D col = lane&15, row = (lane>>4)*4 + reg
  const int fq = lane >> 4;
  #pragma unroll
  for (int mi = 0; mi < 8; ++mi) {
    const size_t row = (size_t)tm * BM + (2 * mi + wm) * 16 + fq * 4;
    #pragma unroll
    for (int ni = 0; ni < 4; ++ni) {
      const size_t col = (size_t)tn * BN + ni * 64 + wn * 16 + fr;
      #pragma unroll
      for (int r = 0; r < 4; ++r)
        Out[(row + r) * N_DIM + col] = acc[mi][ni][r];
    }
  }
}

// ---------------- fallback (round-3 verified path) ----------------

__global__ __launch_bounds__(256) void w8a16_gemm_fb_kernel(
    const float* __restrict__ A, const int* __restrict__ Qw,
    const float* __restrict__ Sc, float* __restrict__ Out)
{
  __shared__ __align__(16) float Asf[2][128 * 32];
  __shared__ __align__(16) f16 Bsf[2][128][32];

  const int t = threadIdx.x, lane = t & 63, wid = t >> 6;
  const int wr = wid >> 1, wc = wid & 1;
  const int nwg = gridDim.x, cpx = nwg >> 3, bid = blockIdx.x;
  const int swz = (bid & 7) * cpx + (bid >> 3);
  const int tn = swz & 31, tm = swz >> 5;
  const size_t a_base = (size_t)tm * 128 * K_DIM;
  const size_t b_base = (size_t)tn * 128 * K_DIM;
  f32x4 acc[4][4] = {};
  const int a_r = t >> 3;
  const int a_slog = (t & 7) ^ ((t >> 3) & 7);

  auto stageA = [&](int buf, int kt) {
    #pragma unroll
    for (int c = 0; c < 4; ++c) {
      const float* g = A + a_base + (size_t)(c * 32 + a_r) * K_DIM + kt * 32 + a_slog * 4;
      char* l = (char*)&Asf[buf][0] + c * 4096 + wid * 1024;
      __builtin_amdgcn_global_load_lds(
          (const __attribute__((address_space(1))) void*)g,
          (__attribute__((address_space(3))) void*)l, 16, 0, 0);
    }
  };
  const int b_r = t >> 3, b_col = (t & 7) * 4;
  auto loadB = [&](int kt, int4* v) {
    #pragma unroll
    for (int c = 0; c < 4; ++c)
      v[c] = *(const int4*)(Qw + b_base + (size_t)(c * 32 + b_r) * K_DIM + kt * 32 + b_col);
  };
  auto writeB = [&](int buf, const int4* v) {
    #pragma unroll
    for (int c = 0; c < 4; ++c) {
      f16x2 lo = cvt2((float)v[c].x, (float)v[c].y);
      f16x2 hi = cvt2((float)v[c].z, (float)v[c].w);
      *(f16x2*)&Bsf[buf][c * 32 + b_r][b_col] = lo;
      *(f16x2*)&Bsf[buf][c * 32 + b_r][b_col + 2] = hi;
    }
  };
  auto compute = [&](int buf) {
    const int fr2 = lane & 15, q = lane >> 4;
    f16x8 af2[4], bf2[4];
    #pragma unroll
    for (int i = 0; i < 4; ++i) {
      const int r = wr * 64 + i * 16 + fr2;
      const float* base = &Asf[buf][0] + r * 32;
      const int s0 = q * 2;
      f32x4 a0 = *(const f32x4*)(base + ((s0 ^ (r & 7)) * 4));
      f32x4 a1 = *(const f32x4*)(base + (((s0 + 1) ^ (r & 7)) * 4));
      f16x2 p0 = cvt2(a0.x, a0.y), p1 = cvt2(a0.z, a0.w);
      f16x2 p2 = cvt2(a1.x, a1.y), p3 = cvt2(a1.z, a1.w);
      af2[i] = (f16x8){p0.x, p0.y, p1.x, p1.y, p2.x, p2.y, p3.x, p3.y};
      bf2[i] = *(const f16x8*)&Bsf[buf][wc * 64 + i * 16 + fr2][q * 8];
    }
    #pragma unroll
    for (int mi = 0; mi < 4; ++mi)
      #pragma unroll
      for (int ni = 0; ni < 4; ++ni)
        acc[mi][ni] = __builtin_amdgcn_mfma_f32_16x16x32_f16(
            af2[mi], bf2[ni], acc[mi][ni], 0, 0, 0);
  };

  { int4 b0[4]; stageA(0, 0); loadB(0, b0); writeB(0, b0); }
  __syncthreads();
  for (int kt = 0; kt < K_DIM / 32; ++kt) {
    const int buf = kt & 1;
    const bool more = (kt + 1) < K_DIM / 32;
    int4 nb[4];
    if (more) { stageA(buf ^ 1, kt + 1); loadB(kt + 1, nb); }
    compute(buf);
    if (more) writeB(buf ^ 1, nb);
    __syncthreads();
  }
  const int fr2 = lane & 15, fq = lane >> 4;
  const int cb = tn * 128 + wc * 64 + fr2;
  const int rb = tm * 128 + wr * 64 + fq * 4;
  #pragma unroll
  for (int ni = 0; ni < 4; ++ni) {
    const float s = Sc[cb + ni * 16];
    #pragma unroll
    for (int mi = 0; mi < 4; ++mi)
      #pragma unroll
      for (int r = 0; r < 4; ++r)
        Out[(size_t)(rb + mi * 16 + r) * N_DIM + (cb + ni * 16)] =
            acc[mi][ni][r] * s;
  }
}

extern "C" void kernel_launch(void* const* d_in, const int* in_sizes, int n_in,
                              void* d_out, int out_size, void* d_ws, size_t ws_size,
                              hipStream_t stream) {
  const float* A  = (const float*)d_in[0];
  const int*   Qw = (const int*)d_in[1];
  const float* Sc = (const float*)d_in[2];
  float*       Out = (float*)d_out;

  const size_t a_bytes = (size_t)M_DIM * K_DIM * sizeof(f16);  // 64 MB
  const size_t w_bytes = (size_t)N_DIM * K_DIM * sizeof(f16);  // 32 MB

  if (ws_size >= a_bytes + w_bytes) {
    f16* Af = (f16*)d_ws;
    f16* Wf = (f16*)((char*)d_ws + a_bytes);
    conv_a_kernel<<<2048, 256, 0, stream>>>(A, Af);
    conv_b_kernel<<<N_DIM, 256, 0, stream>>>(Qw, Sc, Wf);
    dim3 grid((M_DIM / BM) * (N_DIM / BN));  // 32*16 = 512
    w8a16_gemm_f16_kernel<<<grid, 512, 0, stream>>>(Af, Wf, Out);
  } else {
    dim3 grid((M_DIM / 128) * (N_DIM / 128));
    w8a16_gemm_fb_kernel<<<grid, 256, 0, stream>>>(A, Qw, Sc, Out);
  }
}

// Round 13
// 339.045 us; speedup vs baseline: 2.7753x; 2.7737x over previous
//
#include <hip/hip_runtime.h>
#include <stdint.h>

// W8A16 quantized linear, two-phase:
//   Pre-pass: A f32->f16 (64 MB), W = fp16(q*scale) (32 MB) into d_ws.
//   GEMM:     256x256 tile, BK=32, 8 waves (2M x 4N), wave tile 128x64
//             (acc[8][4] in AGPRs), FOUR LDS buffers, 2 phases/K-tile,
//             balanced reads (4 then 8 per wave), 1-phase frag lookahead,
//             2-tile stage lookahead, counted lgkm/vm waits, s_barrier,
//             setprio.
// R11/R12 lesson: 8-wave blocks => 2 waves/SIMD => 256 regs/wave TOTAL
//   (unified). acc=128 AGPR leaves 128 arch VGPRs; R11 exceeded it by a few
//   (offset arrays + per-tile conditional addr temps) -> in-loop spill
//   (WRITE_SIZE 807 MB). Diet here: offset arrays replaced by aoff/boff +
//   compile-time 2048j/4096n immediates (row algebra: 32j==0 mod 16 makes
//   the XOR term j-independent); last 4 tiles peeled so the hot loop is
//   branch-free.
// lgkm ledger (b128): enter p1: [af_top 4, bf 4]; p1 +af_bot 4 -> LGKM(4)
//   retires af_top+bf; p2 reads af_top'+bf' (8) -> LGKM(8) retires af_bot.
// vm ledger (stage insts): enter p1: [kt+1: 4]; p1 +A(kt+2) 2; p2 +B(kt+2)
//   2, VMW(4) retires kt+1 (2-tile slack); tails VMW(0).
// WAR: buffer holding kt last read at p2(kt) (LGKM(8)), sealed by its
//   barrier; restaged at p1(kt+2) - >=1 full tile later.

#define M_DIM 8192
#define N_DIM 4096
#define K_DIM 4096
#define BM 256
#define BN 256
#define BK 32
#define NKT (K_DIM / BK)   // 128 K-tiles

typedef _Float16 f16;
typedef f16 f16x8 __attribute__((ext_vector_type(8)));
typedef f16 f16x2 __attribute__((ext_vector_type(2)));
typedef float f32x4 __attribute__((ext_vector_type(4)));

static __device__ __forceinline__ f16x2 cvt2(float a, float b) {
  return __builtin_bit_cast(f16x2, __builtin_amdgcn_cvt_pkrtz(a, b));
}

// ---------------- pre-pass kernels ----------------

__global__ __launch_bounds__(256) void conv_a_kernel(
    const float* __restrict__ A, f16* __restrict__ Af)
{
  const size_t stride = (size_t)gridDim.x * blockDim.x;
  size_t i = (size_t)blockIdx.x * blockDim.x + threadIdx.x;
  const size_t n8 = (size_t)M_DIM * K_DIM / 8;
  for (; i < n8; i += stride) {
    const f32x4* p = (const f32x4*)(A + i * 8);
    f32x4 v0 = p[0], v1 = p[1];
    f16x2 a = cvt2(v0.x, v0.y), b = cvt2(v0.z, v0.w);
    f16x2 c = cvt2(v1.x, v1.y), d = cvt2(v1.z, v1.w);
    *(f16x8*)(Af + i * 8) = (f16x8){a.x, a.y, b.x, b.y, c.x, c.y, d.x, d.y};
  }
}

__global__ __launch_bounds__(256) void conv_b_kernel(
    const int* __restrict__ Qw, const float* __restrict__ Sc,
    f16* __restrict__ Wf)
{
  const int o = blockIdx.x;
  const int t = threadIdx.x;
  const float s = Sc[o];
  const int* q = Qw + (size_t)o * K_DIM + t * 16;
  f16* w = Wf + (size_t)o * K_DIM + t * 16;
  #pragma unroll
  for (int h = 0; h < 2; ++h) {
    int4 u0 = *(const int4*)(q + h * 8);
    int4 u1 = *(const int4*)(q + h * 8 + 4);
    f16x2 a = cvt2((float)u0.x * s, (float)u0.y * s);
    f16x2 b = cvt2((float)u0.z * s, (float)u0.w * s);
    f16x2 c = cvt2((float)u1.x * s, (float)u1.y * s);
    f16x2 d = cvt2((float)u1.z * s, (float)u1.w * s);
    *(f16x8*)(w + h * 8) = (f16x8){a.x, a.y, b.x, b.y, c.x, c.y, d.x, d.y};
  }
}

// ---------------- main GEMM ----------------

#define BARX() __builtin_amdgcn_s_barrier()
#define SCHED0() __builtin_amdgcn_sched_barrier(0)
#define LGKM(n) do { asm volatile("s_waitcnt lgkmcnt(" #n ")" ::: "memory"); \
                     __builtin_amdgcn_sched_barrier(0); } while (0)
#define VMW(n)  do { asm volatile("s_waitcnt vmcnt(" #n ")" ::: "memory"); \
                     __builtin_amdgcn_sched_barrier(0); } while (0)

// stage one 256x32 f16 tile (16 KB): 2 x global_load_lds(16B)/thread,
// linear LDS dest, inverse-mapped global source (packed-pair XOR layout)
#define STAGE_A(bi, ktn) do { \
  _Pragma("unroll") \
  for (int _i = 0; _i < 2; ++_i) { \
    const f16* _g = aSrc + (size_t)((st_R + 64 * _i) * 2 + st_h) * K_DIM \
                    + (ktn) * BK + st_s * 8; \
    char* _l = (char*)&As[bi][0] + _i * 8192 + wid * 1024; \
    __builtin_amdgcn_global_load_lds( \
        (const __attribute__((address_space(1))) void*)_g, \
        (__attribute__((address_space(3))) void*)_l, 16, 0, 0); \
  } } while (0)

#define STAGE_B(bi, ktn) do { \
  _Pragma("unroll") \
  for (int _i = 0; _i < 2; ++_i) { \
    const f16* _g = bSrc + (size_t)((st_R + 64 * _i) * 2 + st_h) * K_DIM \
                    + (ktn) * BK + st_s * 8; \
    char* _l = (char*)&Bs[bi][0] + _i * 8192 + wid * 1024; \
    __builtin_amdgcn_global_load_lds( \
        (const __attribute__((address_space(1))) void*)_g, \
        (__attribute__((address_space(3))) void*)_l, 16, 0, 0); \
  } } while (0)

// fragment reads: single per-thread offset + compile-time immediates
#define A_LDS(CB, j) (const f16x8*)((const char*)&As[CB][0] + aoff + 2048 * (j))
#define B_LDS(CB, n) (const f16x8*)((const char*)&Bs[CB][0] + boff + 4096 * (n))

#define READ_AF(dst, jb, CB) do { \
  dst[0] = *A_LDS(CB, (jb) + 0); dst[1] = *A_LDS(CB, (jb) + 1); \
  dst[2] = *A_LDS(CB, (jb) + 2); dst[3] = *A_LDS(CB, (jb) + 3); } while (0)

#define READ_BF(dst, CB) do { \
  dst[0] = *B_LDS(CB, 0); dst[1] = *B_LDS(CB, 1); \
  dst[2] = *B_LDS(CB, 2); dst[3] = *B_LDS(CB, 3); } while (0)

// 16 MFMA: m-frags jb..jb+3 x 4 n-frags
#define MFMA_HALF(jb, A_, B_) do { \
  __builtin_amdgcn_s_setprio(1); \
  _Pragma("unroll") \
  for (int _m = 0; _m < 4; ++_m) \
    _Pragma("unroll") \
    for (int _n = 0; _n < 4; ++_n) \
      acc[(jb) + _m][_n] = __builtin_amdgcn_mfma_f32_16x16x32_f16( \
          A_[_m], B_[_n], acc[(jb) + _m][_n], 0, 0, 0); \
  __builtin_amdgcn_s_setprio(0); } while (0)

// One K-tile. CB cur buf, NB next, SB stage target (kt+2).
// M1/M2 are LITERAL 0/1 (folded; hot loop passes 1,1 -> branch-free).
#define TILE(KT, CB, NB, SB, BFC, BFN, M1, M2) do { \
  /* p1: stage A(kt+2); read af_bot(cur); MFMA top */ \
  if (M2) STAGE_A(SB, (KT) + 2); \
  READ_AF(af_bot, 4, CB); \
  BARX(); \
  LGKM(4); \
  MFMA_HALF(0, af_top, BFC); \
  BARX(); \
  /* p2: stage B(kt+2); seal kt+1; read af_top'+bf'(next); MFMA bottom */ \
  if (M2) { STAGE_B(SB, (KT) + 2); VMW(4); } \
  else    { VMW(0); } \
  BARX(); SCHED0(); \
  if (M1) { \
    READ_AF(af_top, 0, NB); \
    READ_BF(BFN, NB); \
    LGKM(8); \
  } else { LGKM(0); } \
  MFMA_HALF(4, af_bot, BFC); \
  BARX(); \
} while (0)

__global__ __launch_bounds__(512, 1) void w8a16_gemm_f16_kernel(
    const f16* __restrict__ Af,   // [M][K]
    const f16* __restrict__ Wf,   // [N][K], scale folded
    float* __restrict__ Out)      // [M][N]
{
  // 4 buffers x 16 KB each operand = 128 KB
  __shared__ __align__(16) f16 As[4][BM * BK];
  __shared__ __align__(16) f16 Bs[4][BN * BK];

  const int t    = threadIdx.x;
  const int lane = t & 63;
  const int wid  = t >> 6;       // 0..7
  const int wm   = wid >> 2;     // 0..1 (M interleave)
  const int wn   = wid & 3;      // 0..3 (N interleave)
  const int fr   = lane & 15;
  const int qk   = lane >> 4;    // k-slot 0..3

  // staging map (thread t, inst i): phys slot f = t + i*512;
  // L=f>>3, w'=f&7, w=w'^(L&7): row=(st_R+64i)*2+st_h, k-slot st_s
  const int st_R = t >> 3;
  const int st_x = (t & 7) ^ (st_R & 7);
  const int st_h = st_x >> 2;
  const int st_s = st_x & 3;

  // fragment read bases (packed-pair XOR layout); per-frag delta is a
  // compile-time immediate: A frag j -> +2048j, B frag n -> +4096n.
  const int ca   = wm * 16 + fr;   // 0..31
  const int aoff = (ca >> 1) * 128
                 + (((((ca & 1) << 2) | qk) ^ ((ca >> 1) & 7)) << 4);
  const int cbv  = wn * 16 + fr;   // 0..63
  const int boff = (cbv >> 1) * 128
                 + (((((cbv & 1) << 2) | qk) ^ ((cbv >> 1) & 7)) << 4);

  // XCD swizzle: 512 blocks, %8==0 -> simple bijective form
  const int bid = blockIdx.x;
  const int swz = (bid & 7) * 64 + (bid >> 3);
  const int tn  = swz & 15;      // 16 N-tiles
  const int tm  = swz >> 4;      // 32 M-tiles

  const f16* aSrc = Af + (size_t)tm * BM * K_DIM;   // block-uniform -> SGPR
  const f16* bSrc = Wf + (size_t)tn * BN * K_DIM;

  f32x4 acc[8][4] = {};
  f16x8 af_top[4], af_bot[4], bfA[4], bfB[4];

  // prologue: stage kt0 -> buf0, kt1 -> buf1; confirm kt0; lookahead reads
  STAGE_A(0, 0); STAGE_B(0, 0);
  STAGE_A(1, 1); STAGE_B(1, 1);
  VMW(4);
  BARX(); SCHED0();
  READ_AF(af_top, 0, 0);
  READ_BF(bfA, 0);

  // hot loop: 31 branch-free groups (kt = 0..120)
  for (int kt = 0; kt < NKT - 4; kt += 4) {
    TILE(kt    , 0, 1, 2, bfA, bfB, 1, 1);
    TILE(kt + 1, 1, 2, 3, bfB, bfA, 1, 1);
    TILE(kt + 2, 2, 3, 0, bfA, bfB, 1, 1);
    TILE(kt + 3, 3, 0, 1, bfB, bfA, 1, 1);
  }
  // peeled final group (kt = 124..127)
  TILE(NKT - 4, 0, 1, 2, bfA, bfB, 1, 1);
  TILE(NKT - 3, 1, 2, 3, bfB, bfA, 1, 1);
  TILE(NKT - 2, 2, 3, 0, bfA, bfB, 1, 0);
  TILE(NKT - 1, 3, 0, 1, bfB, bfA, 0, 0);

  // epilogue: C/D col = lane&15, row = (lane>>4)*4 + reg
  const int fq = lane >> 4;
  #pragma unroll
  for (int mi = 0; mi < 8; ++mi) {
    const size_t row = (size_t)tm * BM + (2 * mi + wm) * 16 + fq * 4;
    #pragma unroll
    for (int ni = 0; ni < 4; ++ni) {
      const size_t col = (size_t)tn * BN + ni * 64 + wn * 16 + fr;
      #pragma unroll
      for (int r = 0; r < 4; ++r)
        Out[(row + r) * N_DIM + col] = acc[mi][ni][r];
    }
  }
}

// ---------------- fallback (round-3 verified path) ----------------

__global__ __launch_bounds__(256) void w8a16_gemm_fb_kernel(
    const float* __restrict__ A, const int* __restrict__ Qw,
    const float* __restrict__ Sc, float* __restrict__ Out)
{
  __shared__ __align__(16) float Asf[2][128 * 32];
  __shared__ __align__(16) f16 Bsf[2][128][32];

  const int t = threadIdx.x, lane = t & 63, wid = t >> 6;
  const int wr = wid >> 1, wc = wid & 1;
  const int nwg = gridDim.x, cpx = nwg >> 3, bid = blockIdx.x;
  const int swz = (bid & 7) * cpx + (bid >> 3);
  const int tn = swz & 31, tm = swz >> 5;
  const size_t a_base = (size_t)tm * 128 * K_DIM;
  const size_t b_base = (size_t)tn * 128 * K_DIM;
  f32x4 acc[4][4] = {};
  const int a_r = t >> 3;
  const int a_slog = (t & 7) ^ ((t >> 3) & 7);

  auto stageA = [&](int buf, int kt) {
    #pragma unroll
    for (int c = 0; c < 4; ++c) {
      const float* g = A + a_base + (size_t)(c * 32 + a_r) * K_DIM + kt * 32 + a_slog * 4;
      char* l = (char*)&Asf[buf][0] + c * 4096 + wid * 1024;
      __builtin_amdgcn_global_load_lds(
          (const __attribute__((address_space(1))) void*)g,
          (__attribute__((address_space(3))) void*)l, 16, 0, 0);
    }
  };
  const int b_r = t >> 3, b_col = (t & 7) * 4;
  auto loadB = [&](int kt, int4* v) {
    #pragma unroll
    for (int c = 0; c < 4; ++c)
      v[c] = *(const int4*)(Qw + b_base + (size_t)(c * 32 + b_r) * K_DIM + kt * 32 + b_col);
  };
  auto writeB = [&](int buf, const int4* v) {
    #pragma unroll
    for (int c = 0; c < 4; ++c) {
      f16x2 lo = cvt2((float)v[c].x, (float)v[c].y);
      f16x2 hi = cvt2((float)v[c].z, (float)v[c].w);
      *(f16x2*)&Bsf[buf][c * 32 + b_r][b_col] = lo;
      *(f16x2*)&Bsf[buf][c * 32 + b_r][b_col + 2] = hi;
    }
  };
  auto compute = [&](int buf) {
    const int fr2 = lane & 15, q = lane >> 4;
    f16x8 af2[4], bf2[4];
    #pragma unroll
    for (int i = 0; i < 4; ++i) {
      const int r = wr * 64 + i * 16 + fr2;
      const float* base = &Asf[buf][0] + r * 32;
      const int s0 = q * 2;
      f32x4 a0 = *(const f32x4*)(base + ((s0 ^ (r & 7)) * 4));
      f32x4 a1 = *(const f32x4*)(base + (((s0 + 1) ^ (r & 7)) * 4));
      f16x2 p0 = cvt2(a0.x, a0.y), p1 = cvt2(a0.z, a0.w);
      f16x2 p2 = cvt2(a1.x, a1.y), p3 = cvt2(a1.z, a1.w);
      af2[i] = (f16x8){p0.x, p0.y, p1.x, p1.y, p2.x, p2.y, p3.x, p3.y};
      bf2[i] = *(const f16x8*)&Bsf[buf][wc * 64 + i * 16 + fr2][q * 8];
    }
    #pragma unroll
    for (int mi = 0; mi < 4; ++mi)
      #pragma unroll
      for (int ni = 0; ni < 4; ++ni)
        acc[mi][ni] = __builtin_amdgcn_mfma_f32_16x16x32_f16(
            af2[mi], bf2[ni], acc[mi][ni], 0, 0, 0);
  };

  { int4 b0[4]; stageA(0, 0); loadB(0, b0); writeB(0, b0); }
  __syncthreads();
  for (int kt = 0; kt < K_DIM / 32; ++kt) {
    const int buf = kt & 1;
    const bool more = (kt + 1) < K_DIM / 32;
    int4 nb[4];
    if (more) { stageA(buf ^ 1, kt + 1); loadB(kt + 1, nb); }
    compute(buf);
    if (more) writeB(buf ^ 1, nb);
    __syncthreads();
  }
  const int fr2 = lane & 15, fq = lane >> 4;
  const int cb = tn * 128 + wc * 64 + fr2;
  const int rb = tm * 128 + wr * 64 + fq * 4;
  #pragma unroll
  for (int ni = 0; ni < 4; ++ni) {
    const float s = Sc[cb + ni * 16];
    #pragma unroll
    for (int mi = 0; mi < 4; ++mi)
      #pragma unroll
      for (int r = 0; r < 4; ++r)
        Out[(size_t)(rb + mi * 16 + r) * N_DIM + (cb + ni * 16)] =
            acc[mi][ni][r] * s;
  }
}

extern "C" void kernel_launch(void* const* d_in, const int* in_sizes, int n_in,
                              void* d_out, int out_size, void* d_ws, size_t ws_size,
                              hipStream_t stream) {
  const float* A  = (const float*)d_in[0];
  const int*   Qw = (const int*)d_in[1];
  const float* Sc = (const float*)d_in[2];
  float*       Out = (float*)d_out;

  const size_t a_bytes = (size_t)M_DIM * K_DIM * sizeof(f16);  // 64 MB
  const size_t w_bytes = (size_t)N_DIM * K_DIM * sizeof(f16);  // 32 MB

  if (ws_size >= a_bytes + w_bytes) {
    f16* Af = (f16*)d_ws;
    f16* Wf = (f16*)((char*)d_ws + a_bytes);
    conv_a_kernel<<<2048, 256, 0, stream>>>(A, Af);
    conv_b_kernel<<<N_DIM, 256, 0, stream>>>(Qw, Sc, Wf);
    dim3 grid((M_DIM / BM) * (N_DIM / BN));  // 32*16 = 512
    w8a16_gemm_f16_kernel<<<grid, 512, 0, stream>>>(Af, Wf, Out);
  } else {
    dim3 grid((M_DIM / 128) * (N_DIM / 128));
    w8a16_gemm_fb_kernel<<<grid, 256, 0, stream>>>(A, Qw, Sc, Out);
  }
}